// Round 1
// baseline (270.867 us; speedup 1.0000x reference)
//
#include <hip/hip_runtime.h>

// ZBL potential:
//   per edge e: s=ei[0][e], d=ei[1][e]
//     a   = 0.4543 / (Zs^0.3 + Zd^0.3)
//     r   = |coord[s] - coord[d] - shift[e]| + 1e-9
//     phi = sum_k c_k * exp(e_k * r/a)
//     E_e = 14.3996 * Zs * Zd / r * phi
//   node_energy  = segment_sum(E_e over src)
//   graph_energy = segment_sum(node_energy over sorted batch)

__global__ void zbl_zero_kernel(float* __restrict__ out, int n) {
    int i = blockIdx.x * blockDim.x + threadIdx.x;
    if (i < n) out[i] = 0.0f;
}

// Hoist pow(Z, 0.3) out of the edge loop: 100k powf instead of 6.4M.
__global__ void zbl_zpow_kernel(const float* __restrict__ species,
                                float* __restrict__ zpow, int n) {
    int i = blockIdx.x * blockDim.x + threadIdx.x;
    if (i < n) zpow[i] = powf(species[i], 0.3f);
}

__global__ void zbl_edge_kernel(const float* __restrict__ coord,
                                const float* __restrict__ species,
                                const float* __restrict__ zpow,
                                const int*   __restrict__ ei,     // [2,E] flat
                                const float* __restrict__ shifts, // [E,3]
                                float* __restrict__ node_e,       // [N]
                                int E) {
    int e = blockIdx.x * blockDim.x + threadIdx.x;
    if (e >= E) return;
    int s = ei[e];
    int d = ei[E + e];

    float zi = species[s];
    float zj = species[d];
    // inv_a = (Zi^0.3 + Zj^0.3) / 0.4543
    float inv_a = (zpow[s] + zpow[d]) * (1.0f / 0.4543f);

    float sx = shifts[3 * e + 0];
    float sy = shifts[3 * e + 1];
    float sz = shifts[3 * e + 2];

    float dx = coord[3 * s + 0] - (coord[3 * d + 0] + sx);
    float dy = coord[3 * s + 1] - (coord[3 * d + 1] + sy);
    float dz = coord[3 * s + 2] - (coord[3 * d + 2] + sz);

    float dist = sqrtf(dx * dx + dy * dy + dz * dz) + 1e-9f;
    float roa  = dist * inv_a;

    float phi = 0.1818f  * __expf(-3.2f    * roa)
              + 0.5099f  * __expf(-0.9423f * roa)
              + 0.2802f  * __expf(-0.4028f * roa)
              + 0.02817f * __expf(-0.2016f * roa);

    float ee = 14.3996f * zi * zj * phi / dist;
    atomicAdd(&node_e[s], ee);
}

// batch is sorted -> wave-aggregate before the atomic (leader loop runs
// ~1-2 iterations per wave; cuts 100k atomics over 256 addrs to ~3k).
__global__ void zbl_graph_kernel(const float* __restrict__ node_e,
                                 const int*   __restrict__ batch,
                                 float* __restrict__ graph_e, int n) {
    int i = blockIdx.x * blockDim.x + threadIdx.x;
    int lane = threadIdx.x & 63;

    float v  = 0.0f;
    int  key = -1;
    if (i < n) { v = node_e[i]; key = batch[i]; }

    unsigned long long active = __ballot(i < n);
    while (active) {
        int leader = (int)__ffsll(active) - 1;
        int lkey   = __shfl(key, leader);
        bool match = (key == lkey) && (i < n);
        unsigned long long mmask = __ballot(match);
        float mv = match ? v : 0.0f;
        #pragma unroll
        for (int off = 32; off > 0; off >>= 1)
            mv += __shfl_xor(mv, off);
        if (lane == leader) atomicAdd(&graph_e[lkey], mv);
        active &= ~mmask;
    }
}

extern "C" void kernel_launch(void* const* d_in, const int* in_sizes, int n_in,
                              void* d_out, int out_size, void* d_ws, size_t ws_size,
                              hipStream_t stream) {
    const float* coord   = (const float*)d_in[0]; // [N,3]
    const float* species = (const float*)d_in[1]; // [N]
    const int*   ei      = (const int*)  d_in[2]; // [2,E]
    const float* shifts  = (const float*)d_in[3]; // [E,3]
    const int*   batch   = (const int*)  d_in[4]; // [N] sorted
    // d_in[5] = num_graphs scalar (on device); G derived from out_size instead.

    int N = in_sizes[1];
    int E = in_sizes[2] / 2;

    float* node_e  = (float*)d_out;      // [N]
    float* graph_e = node_e + N;         // [G]
    float* zpow    = (float*)d_ws;       // [N] scratch

    int threads = 256;
    zbl_zero_kernel<<<(out_size + threads - 1) / threads, threads, 0, stream>>>(
        (float*)d_out, out_size);
    zbl_zpow_kernel<<<(N + threads - 1) / threads, threads, 0, stream>>>(
        species, zpow, N);
    zbl_edge_kernel<<<(E + threads - 1) / threads, threads, 0, stream>>>(
        coord, species, zpow, ei, shifts, node_e, E);
    zbl_graph_kernel<<<(N + threads - 1) / threads, threads, 0, stream>>>(
        node_e, batch, graph_e, N);
}